// Round 19
// baseline (400.694 us; speedup 1.0000x reference)
//
#include <hip/hip_runtime.h>

#define NPATH  2048
#define DIM    64
#define NSTEPS 500
#define PPW    16   // paths per tile (one block per tile, 4 waves)

typedef __attribute__((ext_vector_type(8))) short bf16x8;
typedef __attribute__((ext_vector_type(4))) float f32x4;

union FragU { bf16x8 v; unsigned int u[4]; uint4 q; };

__device__ __forceinline__ unsigned int pk_bf16(float lo, float hi) {
    unsigned int r;
    asm("v_cvt_pk_bf16_f32 %0, %1, %2" : "=v"(r) : "v"(lo), "v"(hi));
    return r;
}

// async HBM->LDS DMA, 16B/lane; dest = wave-uniform base + lane*16 (m104)
__device__ __forceinline__ void dma16(const float* src, float* lds) {
    __builtin_amdgcn_global_load_lds(
        (const __attribute__((address_space(1))) void*)src,
        (__attribute__((address_space(3))) void*)lds, 16, 0, 0);
}

#define MFMA __builtin_amdgcn_mfma_f32_16x16x32_bf16

// r12 structure (verified 138us / absmax 0.03125) with the dW ring moved to
// a global_load_lds DMA pipeline (m201 GEMM-template pattern):
//  - compiler's in-loop vmem = 4 NT stores only (never waited) + the DMA
//    builtin (no result regs) -> compiler emits NO in-loop vmcnt waits;
//  - our counted s_waitcnt vmcnt(16)+sched_barrier(0) at the step top guards
//    the slot DMA'd 7 steps ago (>=34 vmem ops after it; steady-state
//    outstanding ~13 -> wait is free); safe under unknown spill traffic.
//  - DMA lane = 16B = 4 dims of one path; slot float idx pp*16+d == 4*lane+e
//    identity, so lane-linear DMA dest matches the (4h+j)*16+c consume reads.
//  - DMA at step S targets slot (S+7)&7 == the slot read at step S-1 ->
//    ordered by the intervening barrier, race-free.
// Exchange (xt bf16 ping-pong, XOR swizzle, lgkm-only drain + raw barrier)
// and all arithmetic identical to r12.
__global__ __launch_bounds__(256, 1) void sde_mfma_dma_kernel(
    const float* __restrict__ x0,
    const float* __restrict__ dW,
    const float* __restrict__ drift,
    const float* __restrict__ drift_bias,
    const float* __restrict__ diffusion,
    const float* __restrict__ diffusion_bias,
    const float* __restrict__ ts,
    float* __restrict__ out)
{
    __shared__ __align__(16) unsigned short xt[2][PPW * DIM];  // 4 KB
    __shared__ __align__(16) float ring[4][8][256];            // 32 KB dW ring
    __shared__ float2 dtp[NSTEPS + 1];                         // 4 KB

    const int tid   = threadIdx.x;
    const int wn    = tid >> 6;          // wave = output-dim quarter
    const int lane  = tid & 63;
    const int c     = lane & 15;
    const int h     = lane >> 4;
    const int pbase = blockIdx.x * PPW;
    const int mydim = 16 * wn + c;

    for (int i = tid; i < NSTEPS; i += 256) {
        const float d = ts[i + 1] - ts[i];          // f32-exact vs reference
        dtp[i] = make_float2(d, sqrtf(d));
    }
    if (tid == 0) dtp[NSTEPS] = make_float2(0.f, 0.f);

    // B-frags for this wave's quarter (verified k-packing)
    FragU bd0, bd1, bs0, bs1;
    {
        const float* Ar = drift     + mydim * DIM + 8 * h;
        const float* Cr = diffusion + mydim * DIM + 8 * h;
        float4 t;
        t = *(const float4*)(Ar +  0); bd0.u[0] = pk_bf16(t.x, t.y); bd0.u[1] = pk_bf16(t.z, t.w);
        t = *(const float4*)(Ar +  4); bd0.u[2] = pk_bf16(t.x, t.y); bd0.u[3] = pk_bf16(t.z, t.w);
        t = *(const float4*)(Ar + 32); bd1.u[0] = pk_bf16(t.x, t.y); bd1.u[1] = pk_bf16(t.z, t.w);
        t = *(const float4*)(Ar + 36); bd1.u[2] = pk_bf16(t.x, t.y); bd1.u[3] = pk_bf16(t.z, t.w);
        t = *(const float4*)(Cr +  0); bs0.u[0] = pk_bf16(t.x, t.y); bs0.u[1] = pk_bf16(t.z, t.w);
        t = *(const float4*)(Cr +  4); bs0.u[2] = pk_bf16(t.x, t.y); bs0.u[3] = pk_bf16(t.z, t.w);
        t = *(const float4*)(Cr + 32); bs1.u[0] = pk_bf16(t.x, t.y); bs1.u[1] = pk_bf16(t.z, t.w);
        t = *(const float4*)(Cr + 36); bs1.u[2] = pk_bf16(t.x, t.y); bs1.u[3] = pk_bf16(t.z, t.w);
    }
    const float bdr = drift_bias[mydim];
    const float bdi = diffusion_bias[mydim];
    const f32x4 cbA = {bdr, bdr, bdr, bdr};     // C-init: bias (k0 half)
    const f32x4 cbC = {bdi, bdi, bdi, bdi};
    const f32x4 cz  = {0.f, 0.f, 0.f, 0.f};    // C-init: zero (k1 half)

    // state (4 paths x this lane's dim), pointers, xt write offsets
    float xst[4];
    float* op[4];
    unsigned int woff[4];
#pragma unroll
    for (int j = 0; j < 4; ++j) {
        const int pp = 4 * h + j;
        const int p  = pbase + pp;
        op[j]  = out + (size_t)p * (NSTEPS + 1) * DIM + mydim;
        woff[j] = (unsigned)((pp * 32 + ((mydim >> 1) ^ ((pp & 7) << 2))) * 2 + (c & 1));
        const float v = x0[p * DIM + mydim];
        xst[j] = v;
        *op[j] = v;                                     // ys[:,0,:]
        op[j] += DIM;                                   // -> row 1
        xt[0][woff[j]] = (unsigned short)pk_bf16(v, v); // x tile for step 0
    }

    // step-invariant xt read offsets (uint4 granularity; swizzle folded in)
    const int ra0 = c * 8 + (h ^ (c & 7));          // dims 8h+0..7   of path c
    const int ra1 = c * 8 + ((4 + h) ^ (c & 7));    // dims 32+8h+0..7
    const uint4* xr0 = (const uint4*)xt[0];
    const uint4* xr1 = (const uint4*)xt[1];
    unsigned short* xw0 = xt[0];
    unsigned short* xw1 = xt[1];

    // DMA lane source: 16B = dims [16wn+4*(lane&3) .. +3] of path (lane>>2)
    const float* pdma = dW + (size_t)(pbase + (lane >> 2)) * NSTEPS * DIM
                           + 16 * wn + 4 * (lane & 3);
    float (*ringw)[256] = ring[wn];
    const int rbase = h * 64 + c;        // consume idx: rbase + 16*j

    // prologue: DMA steps 0..6 into slots 0..6, drain once, sync
#pragma unroll
    for (int s = 0; s < 7; ++s)
        dma16(pdma + (size_t)s * DIM, &ringw[s][0]);
    pdma += 7 * DIM;                     // now points at step 7

    asm volatile("s_waitcnt vmcnt(0)" ::: "memory");
    __builtin_amdgcn_sched_barrier(0);
    __syncthreads();                     // xt[0], dtp, slots 0..6 ready

    float2 dts = dtp[0];
    const float2* pdt = &dtp[1];

    // Step S (K = S&7): our vmcnt(16) guards slot K (DMA'd at S-7 with >=34
    // vmem ops after it). DMA refills slot (K+7)&7 (read at step S-1, ordered
    // by the barrier). lgkm-only drain before the raw barrier (T3/T4).
#define STEP(K, DODMA, XR, XW)                                                \
    {                                                                         \
        asm volatile("s_waitcnt vmcnt(16)" ::: "memory");                     \
        __builtin_amdgcn_sched_barrier(0);                                    \
        FragU a0, a1;                                                         \
        a0.q = XR[ra0];                                                       \
        a1.q = XR[ra1];                                                       \
        const float r0 = ringw[K][rbase +  0];                                \
        const float r1 = ringw[K][rbase + 16];                                \
        const float r2 = ringw[K][rbase + 32];                                \
        const float r3 = ringw[K][rbase + 48];                                \
        if (DODMA) dma16(pdma, &ringw[(K + 7) & 7][0]);                       \
        pdma += DIM;                                                          \
        const float2 dtn = *pdt++;                                            \
        const f32x4 adA = MFMA(a0.v, bd0.v, cbA, 0, 0, 0);                    \
        const f32x4 adB = MFMA(a1.v, bd1.v, cz,  0, 0, 0);                    \
        const f32x4 ciA = MFMA(a0.v, bs0.v, cbC, 0, 0, 0);                    \
        const f32x4 ciB = MFMA(a1.v, bs1.v, cz,  0, 0, 0);                    \
        const float srw[4] = {dts.y * r0, dts.y * r1, dts.y * r2, dts.y * r3};\
        _Pragma("unroll")                                                     \
        for (int j = 0; j < 4; ++j) {                                         \
            const float ad = adA[j] + adB[j];                                 \
            const float ci = ciA[j] + ciB[j];                                 \
            const float xn = fmaf(dts.x, ad, xst[j]) + ci * srw[j];           \
            xst[j] = xn;                                                      \
            __builtin_nontemporal_store(xn, op[j]);                           \
            op[j] += DIM;                                                     \
            XW[woff[j]] = (unsigned short)pk_bf16(xn, xn);                    \
        }                                                                     \
        dts = dtn;                                                            \
        asm volatile("s_waitcnt lgkmcnt(0)" ::: "memory");                    \
        __builtin_amdgcn_s_barrier();                                         \
        __builtin_amdgcn_sched_barrier(0);                                    \
    }

    // main loop: 61 x 8 = steps 0..487 (DMA targets steps 7..494)
    for (int it = 0; it < 61; ++it) {
        STEP(0, 1, xr0, xw1)
        STEP(1, 1, xr1, xw0)
        STEP(2, 1, xr0, xw1)
        STEP(3, 1, xr1, xw0)
        STEP(4, 1, xr0, xw1)
        STEP(5, 1, xr1, xw0)
        STEP(6, 1, xr0, xw1)
        STEP(7, 1, xr1, xw0)
    }
    // steps 488..492: DMA targets steps 495..499 (last valid)
    STEP(0, 1, xr0, xw1)
    STEP(1, 1, xr1, xw0)
    STEP(2, 1, xr0, xw1)
    STEP(3, 1, xr1, xw0)
    STEP(4, 1, xr0, xw1)
    // steps 493..499: no DMA
    STEP(5, 0, xr1, xw0)
    STEP(6, 0, xr0, xw1)
    STEP(7, 0, xr1, xw0)
    STEP(0, 0, xr0, xw1)
    STEP(1, 0, xr1, xw0)
    STEP(2, 0, xr0, xw1)
    STEP(3, 0, xr1, xw0)
#undef STEP
}

extern "C" void kernel_launch(void* const* d_in, const int* in_sizes, int n_in,
                              void* d_out, int out_size, void* d_ws, size_t ws_size,
                              hipStream_t stream) {
    const float* x0             = (const float*)d_in[0];
    const float* dW             = (const float*)d_in[1];
    const float* drift          = (const float*)d_in[2];
    const float* drift_bias     = (const float*)d_in[3];
    const float* diffusion      = (const float*)d_in[4];
    const float* diffusion_bias = (const float*)d_in[5];
    const float* ts             = (const float*)d_in[6];
    float* out = (float*)d_out;

    dim3 grid(NPATH / PPW);   // 128 blocks (one 16-path tile each)
    dim3 block(256);          // 4 waves
    hipLaunchKernelGGL(sde_mfma_dma_kernel, grid, block, 0, stream,
                       x0, dW, drift, drift_bias, diffusion, diffusion_bias,
                       ts, out);
}

// Round 20
// 138.201 us; speedup vs baseline: 2.8994x; 2.8994x over previous
//
#include <hip/hip_runtime.h>

#define NPATH  2048
#define DIM    64
#define NSTEPS 500
#define PPW    16   // paths per tile (one block per tile, 4 waves)

typedef __attribute__((ext_vector_type(8))) short bf16x8;
typedef __attribute__((ext_vector_type(4))) float f32x4;

union FragU { bf16x8 v; unsigned int u[4]; uint4 q; };

__device__ __forceinline__ unsigned int pk_bf16(float lo, float hi) {
    unsigned int r;
    asm("v_cvt_pk_bf16_f32 %0, %1, %2" : "=v"(r) : "v"(lo), "v"(hi));
    return r;
}

#define MFMA __builtin_amdgcn_mfma_f32_16x16x32_bf16

// SESSION-BEST (round 12, verified 138.2us, absmax 0.03125), restored verbatim.
// One block = one 16-path tile, 4 waves; wave wn owns output dims
// [16wn,16wn+16). Matrix frags (4 x 16B) in VGPRs. State tile xt: bf16 in
// LDS, ping-pong, XOR-swizzled (0 bank conflicts measured). One raw barrier
// per step, lgkmcnt-only drain (dW ring never vmcnt-drained by us).
// Independent MFMA pairs (C=bias / C=0 + VALU add); ds_read at phase top
// with srw precompute + ring prefetch under its latency; ring depth 8;
// pointer-increment stores; launch_bounds(256,1).
__global__ __launch_bounds__(256, 1) void sde_mfma_mw2_kernel(
    const float* __restrict__ x0,
    const float* __restrict__ dW,
    const float* __restrict__ drift,
    const float* __restrict__ drift_bias,
    const float* __restrict__ diffusion,
    const float* __restrict__ diffusion_bias,
    const float* __restrict__ ts,
    float* __restrict__ out)
{
    __shared__ __align__(16) unsigned short xt[2][PPW * DIM];  // bf16, swizzled
    __shared__ float2 dtp[NSTEPS + 1];

    const int tid   = threadIdx.x;
    const int wn    = tid >> 6;          // wave = output-dim quarter
    const int lane  = tid & 63;
    const int c     = lane & 15;
    const int h     = lane >> 4;
    const int pbase = blockIdx.x * PPW;
    const int mydim = 16 * wn + c;

    for (int i = tid; i < NSTEPS; i += 256) {
        const float d = ts[i + 1] - ts[i];          // f32-exact vs reference
        dtp[i] = make_float2(d, sqrtf(d));
    }
    if (tid == 0) dtp[NSTEPS] = make_float2(0.f, 0.f);

    // B-frags for this wave's quarter (verified k-packing: lane (c,h)
    // holds M[mydim][32*kk + 8*h + e], e=0..7, matching the A-side packing)
    FragU bd0, bd1, bs0, bs1;
    {
        const float* Ar = drift     + mydim * DIM + 8 * h;
        const float* Cr = diffusion + mydim * DIM + 8 * h;
        float4 t;
        t = *(const float4*)(Ar +  0); bd0.u[0] = pk_bf16(t.x, t.y); bd0.u[1] = pk_bf16(t.z, t.w);
        t = *(const float4*)(Ar +  4); bd0.u[2] = pk_bf16(t.x, t.y); bd0.u[3] = pk_bf16(t.z, t.w);
        t = *(const float4*)(Ar + 32); bd1.u[0] = pk_bf16(t.x, t.y); bd1.u[1] = pk_bf16(t.z, t.w);
        t = *(const float4*)(Ar + 36); bd1.u[2] = pk_bf16(t.x, t.y); bd1.u[3] = pk_bf16(t.z, t.w);
        t = *(const float4*)(Cr +  0); bs0.u[0] = pk_bf16(t.x, t.y); bs0.u[1] = pk_bf16(t.z, t.w);
        t = *(const float4*)(Cr +  4); bs0.u[2] = pk_bf16(t.x, t.y); bs0.u[3] = pk_bf16(t.z, t.w);
        t = *(const float4*)(Cr + 32); bs1.u[0] = pk_bf16(t.x, t.y); bs1.u[1] = pk_bf16(t.z, t.w);
        t = *(const float4*)(Cr + 36); bs1.u[2] = pk_bf16(t.x, t.y); bs1.u[3] = pk_bf16(t.z, t.w);
    }
    const float bdr = drift_bias[mydim];
    const float bdi = diffusion_bias[mydim];
    const f32x4 cbA = {bdr, bdr, bdr, bdr};     // C-init: bias (k0 half)
    const f32x4 cbC = {bdi, bdi, bdi, bdi};
    const f32x4 cz  = {0.f, 0.f, 0.f, 0.f};    // C-init: zero (k1 half)

    // state (4 paths x this lane's dim), pointers, xt write offsets
    float xst[4];
    const float* dwq[4];
    float* op[4];
    unsigned int woff[4];
#pragma unroll
    for (int j = 0; j < 4; ++j) {
        const int pp = 4 * h + j;
        const int p  = pbase + pp;
        dwq[j] = dW  + (size_t)p * NSTEPS * DIM + mydim;
        op[j]  = out + (size_t)p * (NSTEPS + 1) * DIM + mydim;
        woff[j] = (unsigned)((pp * 32 + ((mydim >> 1) ^ ((pp & 7) << 2))) * 2 + (c & 1));
        const float v = x0[p * DIM + mydim];
        xst[j] = v;
        __builtin_nontemporal_store(v, op[j]);          // ys[:,0,:]
        op[j] += DIM;                                   // -> row 1
        xt[0][woff[j]] = (unsigned short)pk_bf16(v, v); // x tile for step 0
    }

    // step-invariant read offsets (uint4 granularity; swizzle folded in)
    const int ra0 = c * 8 + (h ^ (c & 7));          // dims 8h+0..7   of path c
    const int ra1 = c * 8 + ((4 + h) ^ (c & 7));    // dims 32+8h+0..7
    const uint4* xr0 = (const uint4*)xt[0];
    const uint4* xr1 = (const uint4*)xt[1];
    unsigned short* xw0 = xt[0];
    unsigned short* xw1 = xt[1];

    // dW prefetch ring, depth 8 (named rings, static indices only)
    float R0[4], R1[4], R2[4], R3[4], R4[4], R5[4], R6[4], R7[4];
#pragma unroll
    for (int j = 0; j < 4; ++j) {
        R0[j] = dwq[j][0 * DIM]; R1[j] = dwq[j][1 * DIM];
        R2[j] = dwq[j][2 * DIM]; R3[j] = dwq[j][3 * DIM];
        R4[j] = dwq[j][4 * DIM]; R5[j] = dwq[j][5 * DIM];
        R6[j] = dwq[j][6 * DIM]; R7[j] = dwq[j][7 * DIM];
        dwq[j] += 8 * DIM;               // now points at step s+8
    }

    __syncthreads();                     // one-time full sync (xt[0], dtp ready)

    float2 dts = dtp[0];                 // {dt, sdt} current step

    // Phase layout: ds_read first (chain head); srw precompute + ring
    // prefetch issue under the read latency; 4 independent MFMAs; update;
    // NT store + bf16 xt write; lgkm-only drain; raw barrier.
#define STEP(S, R, PF, KOFF, XR, XW)                                          \
    {                                                                         \
        FragU a0, a1;                                                         \
        a0.q = XR[ra0];                                                       \
        a1.q = XR[ra1];                                                       \
        const float srw0 = dts.y * R[0];  /* consume ring before overwrite */ \
        const float srw1 = dts.y * R[1];                                      \
        const float srw2 = dts.y * R[2];                                      \
        const float srw3 = dts.y * R[3];                                      \
        if (PF) {                                                             \
            R[0] = dwq[0][(KOFF) * DIM];                                      \
            R[1] = dwq[1][(KOFF) * DIM];                                      \
            R[2] = dwq[2][(KOFF) * DIM];                                      \
            R[3] = dwq[3][(KOFF) * DIM];                                      \
        }                                                                     \
        const float2 dtn = dtp[(S) + 1];                                      \
        const f32x4 adA = MFMA(a0.v, bd0.v, cbA, 0, 0, 0);                    \
        const f32x4 adB = MFMA(a1.v, bd1.v, cz,  0, 0, 0);                    \
        const f32x4 ciA = MFMA(a0.v, bs0.v, cbC, 0, 0, 0);                    \
        const f32x4 ciB = MFMA(a1.v, bs1.v, cz,  0, 0, 0);                    \
        const float srw[4] = {srw0, srw1, srw2, srw3};                        \
        _Pragma("unroll")                                                     \
        for (int j = 0; j < 4; ++j) {                                         \
            const float ad = adA[j] + adB[j];                                 \
            const float ci = ciA[j] + ciB[j];                                 \
            const float xn = fmaf(dts.x, ad, xst[j]) + ci * srw[j];           \
            xst[j] = xn;                                                      \
            __builtin_nontemporal_store(xn, op[j]);                           \
            op[j] += DIM;                                                     \
            XW[woff[j]] = (unsigned short)pk_bf16(xn, xn);                    \
        }                                                                     \
        dts = dtn;                                                            \
        asm volatile("s_waitcnt lgkmcnt(0)" ::: "memory");                    \
        __builtin_amdgcn_s_barrier();                                         \
        __builtin_amdgcn_sched_barrier(0);                                    \
    }

    // main loop: 61 x 8 = steps 0..487, prefetching steps 8..495
    for (int it = 0; it < 61; ++it) {
        const int s = it * 8;
        STEP(s + 0, R0, 1, 0, xr0, xw1)
        STEP(s + 1, R1, 1, 1, xr1, xw0)
        STEP(s + 2, R2, 1, 2, xr0, xw1)
        STEP(s + 3, R3, 1, 3, xr1, xw0)
        STEP(s + 4, R4, 1, 4, xr0, xw1)
        STEP(s + 5, R5, 1, 5, xr1, xw0)
        STEP(s + 6, R6, 1, 6, xr0, xw1)
        STEP(s + 7, R7, 1, 7, xr1, xw0)
#pragma unroll
        for (int j = 0; j < 4; ++j) dwq[j] += 8 * DIM;
    }
    // tail 1: steps 488..495; prefetch only steps 496..499 (k<4)
    {
        STEP(488, R0, 1, 0, xr0, xw1)
        STEP(489, R1, 1, 1, xr1, xw0)
        STEP(490, R2, 1, 2, xr0, xw1)
        STEP(491, R3, 1, 3, xr1, xw0)
        STEP(492, R4, 0, 0, xr0, xw1)
        STEP(493, R5, 0, 0, xr1, xw0)
        STEP(494, R6, 0, 0, xr0, xw1)
        STEP(495, R7, 0, 0, xr1, xw0)
    }
    // tail 2: steps 496..499, no prefetch
    {
        STEP(496, R0, 0, 0, xr0, xw1)
        STEP(497, R1, 0, 0, xr1, xw0)
        STEP(498, R2, 0, 0, xr0, xw1)
        STEP(499, R3, 0, 0, xr1, xw0)
    }
#undef STEP
}

extern "C" void kernel_launch(void* const* d_in, const int* in_sizes, int n_in,
                              void* d_out, int out_size, void* d_ws, size_t ws_size,
                              hipStream_t stream) {
    const float* x0             = (const float*)d_in[0];
    const float* dW             = (const float*)d_in[1];
    const float* drift          = (const float*)d_in[2];
    const float* drift_bias     = (const float*)d_in[3];
    const float* diffusion      = (const float*)d_in[4];
    const float* diffusion_bias = (const float*)d_in[5];
    const float* ts             = (const float*)d_in[6];
    float* out = (float*)d_out;

    dim3 grid(NPATH / PPW);   // 128 blocks (one 16-path tile each)
    dim3 block(256);          // 4 waves
    hipLaunchKernelGGL(sde_mfma_mw2_kernel, grid, block, 0, stream,
                       x0, dW, drift, drift_bias, diffusion, diffusion_bias,
                       ts, out);
}